// Round 6
// baseline (110.320 us; speedup 1.0000x reference)
//
#include <hip/hip_runtime.h>
#include <math.h>

#define PH 7
#define PW 7
#define B_ 4
#define C_ 256
#define H_ 50
#define W_ 50
#define R_ 256
#define S_ (H_ * W_)     // 2500
#define NCELL (PH * PW)  // 49
#define MAXW 9           // max window width: ceil(50/7)+1

// ---------- kernel 1: features (B,C,H,W) -> (B,H,W,C) ----------
__global__ void transpose_chw_hwc(const float* __restrict__ in, float* __restrict__ out) {
    __shared__ float tile[32][33];
    const int b  = blockIdx.z;
    const int s0 = blockIdx.x * 32;
    const int c0 = blockIdx.y * 32;
    const float* inb  = in  + (size_t)b * C_ * S_;
    float*       outb = out + (size_t)b * S_ * C_;
    const int tx = threadIdx.x;
    #pragma unroll
    for (int i = threadIdx.y; i < 32; i += 8) {
        const int s = s0 + tx;
        if (s < S_) tile[i][tx] = inb[(size_t)(c0 + i) * S_ + s];
    }
    __syncthreads();
    #pragma unroll
    for (int i = threadIdx.y; i < 32; i += 8) {
        const int s = s0 + i;
        if (s < S_) outb[(size_t)s * C_ + (c0 + tx)] = tile[tx][i];
    }
}

__device__ __forceinline__ float4 max4(float4 a, float4 b) {
    a.x = fmaxf(a.x, b.x); a.y = fmaxf(a.y, b.y);
    a.z = fmaxf(a.z, b.z); a.w = fmaxf(a.w, b.w);
    return a;
}

// ---------- kernel 2: pool. One wave per (roi, row-band). ----------
// The wave computes ALL 7 col-windows of its band: acc[q] statically indexed
// (q-loop unrolled). Col-window boundary duplicates are re-loads of data this
// wave just touched -> L1 hits, off the LLC path. Only band-boundary rows
// (<=6 per roi) remain cross-block. LLC traffic (h+6)(w+6) -> (h+6)*w per roi
// (~144 -> ~107 MB total). Loads stay 1 KB coalesced.
__global__ void __launch_bounds__(64, 4)
roi_pool_band(const float* __restrict__ ft, const int* __restrict__ rois,
              float* __restrict__ tmp) {
    const int bx   = blockIdx.x;
    const int r    = bx / PH;        // 0..255
    const int ph   = bx - r * PH;    // 0..6
    const int lane = threadIdx.x;    // 0..63

    const int* roi = rois + r * 5;
    const int b  = roi[0];
    const int x1 = roi[1] >> 4;   // floor(v/16), v >= 0
    const int y1 = roi[2] >> 4;
    const int x2 = roi[3] >> 4;
    const int y2 = roi[4] >> 4;
    const int h = y2 - y1 + 1;
    const int w = x2 - x1 + 1;

    const int sh = y1 + (ph * h) / PH;
    const int eh = y1 + ((ph + 1) * h + PH - 1) / PH;

    int sw[PW], kw[PW];
    #pragma unroll
    for (int q = 0; q < PW; ++q) {
        sw[q] = x1 + (q * w) / PW;
        kw[q] = x1 + ((q + 1) * w + PW - 1) / PW - sw[q];   // 1..9, uniform
    }

    const float* fb = ft + (size_t)b * S_ * C_ + 4 * lane;

    float4 acc[PW];
    #pragma unroll
    for (int q = 0; q < PW; ++q)
        acc[q] = make_float4(-INFINITY, -INFINITY, -INFINITY, -INFINITY);

    int y = sh;
    if ((eh - sh) & 1) {             // odd band height: single-row prologue
        const float* row0 = fb + (size_t)(y * W_) * C_;
        #pragma unroll
        for (int q = 0; q < PW; ++q) {
            const float* p0 = row0 + (size_t)sw[q] * C_;
            float4 v0[MAXW];
            #pragma unroll
            for (int k = 0; k < MAXW; ++k)
                if (k < kw[q]) v0[k] = *(const float4*)(p0 + (size_t)k * C_);
            #pragma unroll
            for (int k = 0; k < MAXW; ++k)
                if (k < kw[q]) acc[q] = max4(acc[q], v0[k]);
        }
        ++y;
    }
    for (; y < eh; y += 2) {         // even remainder: true row pairs
        const float* row0 = fb + (size_t)( y      * W_) * C_;
        const float* row1 = fb + (size_t)((y + 1) * W_) * C_;
        #pragma unroll
        for (int q = 0; q < PW; ++q) {   // v0/v1 live only within one q step
            const float* p0 = row0 + (size_t)sw[q] * C_;
            const float* p1 = row1 + (size_t)sw[q] * C_;
            float4 v0[MAXW], v1[MAXW];
            #pragma unroll
            for (int k = 0; k < MAXW; ++k) {
                if (k < kw[q]) {                     // wave-uniform branch
                    v0[k] = *(const float4*)(p0 + (size_t)k * C_);
                    v1[k] = *(const float4*)(p1 + (size_t)k * C_);
                }
            }
            #pragma unroll
            for (int k = 0; k < MAXW; ++k) {
                if (k < kw[q]) acc[q] = max4(acc[q], max4(v0[k], v1[k]));
            }
        }
    }

    // 7 cells, 7 KB contiguous per wave
    float* dst = tmp + ((size_t)(r * NCELL + ph * PW)) * C_ + 4 * lane;
    #pragma unroll
    for (int q = 0; q < PW; ++q)
        *(float4*)(dst + (size_t)q * C_) = acc[q];
}

// ---------- kernel 3: tmp (R,49,C) -> out (R,C,49) ----------
__global__ void __launch_bounds__(256)
transpose_out(const float* __restrict__ tmp, float* __restrict__ out) {
    __shared__ float lds[NCELL * 129];  // 25.3 KB
    const int r    = blockIdx.x >> 1;
    const int c0   = (blockIdx.x & 1) << 7;   // 0 or 128
    const int t    = threadIdx.x;
    const float* src = tmp + (size_t)r * NCELL * C_ + c0;
    float*       dst = out + (size_t)r * C_ * NCELL + (size_t)c0 * NCELL;

    #pragma unroll
    for (int i = t; i < NCELL * 128; i += 256) {
        const int cell = i >> 7;         // i = cell*128 + c
        const int c    = i & 127;
        lds[cell * 129 + c] = src[(size_t)cell * C_ + c];
    }
    __syncthreads();
    #pragma unroll
    for (int f = t; f < 128 * NCELL; f += 256) {
        const int c    = f / NCELL;      // const divisor -> magic mul
        const int cell = f - c * NCELL;  // f = c*49 + cell
        dst[f] = lds[cell * 129 + c];
    }
}

extern "C" void kernel_launch(void* const* d_in, const int* in_sizes, int n_in,
                              void* d_out, int out_size, void* d_ws, size_t ws_size,
                              hipStream_t stream) {
    const float* features = (const float*)d_in[0];
    const int*   rois     = (const int*)d_in[1];
    float*       out      = (float*)d_out;

    float* ft  = (float*)d_ws;                       // 10.24 MB
    float* tmp = ft + (size_t)B_ * S_ * C_;          // +12.85 MB (ws is 256 MB)

    dim3 tgrid((S_ + 31) / 32, C_ / 32, B_);
    transpose_chw_hwc<<<tgrid, dim3(32, 8), 0, stream>>>(features, ft);
    roi_pool_band<<<R_ * PH, 64, 0, stream>>>(ft, rois, tmp);
    transpose_out<<<R_ * 2, 256, 0, stream>>>(tmp, out);
}